// Round 6
// baseline (3707.833 us; speedup 1.0000x reference)
//
#include <hip/hip_runtime.h>
#include <float.h>
#include <math.h>

#define B_    128
#define H_    512
#define V_    1000
#define T_    256
#define G4_   2048
#define NBLK  256          // cooperative launch: 1 block/CU
#define SPIN_MAX (1 << 17) // bounded spin: converts would-be hang into wrong-answer

#define AT_LOAD(p)    __hip_atomic_load((p), __ATOMIC_RELAXED, __HIP_MEMORY_SCOPE_AGENT)
#define AT_STORE(p,v) __hip_atomic_store((p), (v), __ATOMIC_RELAXED, __HIP_MEMORY_SCOPE_AGENT)

__device__ __forceinline__ float dot4(float4 a, float4 b, float acc) {
  return fmaf(a.x, b.x, fmaf(a.y, b.y, fmaf(a.z, b.z, fmaf(a.w, b.w, acc))));
}

// 16-lane butterfly sum, pure DPP (VALU pipe, zero LDS traffic).
__device__ __forceinline__ float red16(float x) {
  x += __int_as_float(__builtin_amdgcn_mov_dpp(__float_as_int(x), 0xB1,  0xF, 0xF, true));
  x += __int_as_float(__builtin_amdgcn_mov_dpp(__float_as_int(x), 0x4E,  0xF, 0xF, true));
  x += __int_as_float(__builtin_amdgcn_mov_dpp(__float_as_int(x), 0x141, 0xF, 0xF, true));
  x += __int_as_float(__builtin_amdgcn_mov_dpp(__float_as_int(x), 0x140, 0xF, 0xF, true));
  return x;
}

// ---------------------------------------------------------------------------
// Precompute GEMM:  C = A[M][0:512] * Bm[N][koff:+512]^T (+bias1+bias2).
// ileave=1 stores gate-interleaved: C[m][ (n&511)*4 + (n>>9) ]  (ldc=2048),
// so the decoder reads all 4 gates of one unit as a single float4.
// ---------------------------------------------------------------------------
__global__ __launch_bounds__(256) void gemm_nt_k512(
    const float* __restrict__ A, int M,
    const float* __restrict__ Bm, int ldb, int koff,
    const float* __restrict__ bias1, const float* __restrict__ bias2,
    float* __restrict__ C, int ldc, int ileave)
{
  __shared__ float As[16][68];
  __shared__ float Bs[16][68];
  const int tid = threadIdx.x;
  const int m0 = blockIdx.y * 64, n0 = blockIdx.x * 64;
  const int tm = tid & 15, tn = tid >> 4;
  const int lm = tid & 63, kq = tid >> 6;
  float acc[4][4] = {};
  for (int k0 = 0; k0 < 512; k0 += 16) {
    float4 av = make_float4(0.f, 0.f, 0.f, 0.f);
    if (m0 + lm < M) av = *(const float4*)(A + (size_t)(m0 + lm) * 512 + k0 + kq * 4);
    float4 bv = *(const float4*)(Bm + (size_t)(n0 + lm) * ldb + koff + k0 + kq * 4);
    __syncthreads();
    As[kq*4+0][lm] = av.x; As[kq*4+1][lm] = av.y; As[kq*4+2][lm] = av.z; As[kq*4+3][lm] = av.w;
    Bs[kq*4+0][lm] = bv.x; Bs[kq*4+1][lm] = bv.y; Bs[kq*4+2][lm] = bv.z; Bs[kq*4+3][lm] = bv.w;
    __syncthreads();
#pragma unroll
    for (int kk = 0; kk < 16; ++kk) {
      const float4 a = *(const float4*)&As[kk][tm * 4];
      const float4 b = *(const float4*)&Bs[kk][tn * 4];
      const float aa[4] = {a.x, a.y, a.z, a.w};
      const float bb[4] = {b.x, b.y, b.z, b.w};
#pragma unroll
      for (int i = 0; i < 4; ++i)
#pragma unroll
        for (int j = 0; j < 4; ++j)
          acc[i][j] = fmaf(aa[i], bb[j], acc[i][j]);
    }
  }
#pragma unroll
  for (int i = 0; i < 4; ++i) {
    const int m = m0 + tm * 4 + i;
    if (m < M) {
#pragma unroll
      for (int j = 0; j < 4; ++j) {
        const int n = n0 + tn * 4 + j;
        float v = acc[i][j];
        if (bias1) v += bias1[n];
        if (bias2) v += bias2[n];
        const size_t idx = ileave ? ((size_t)m * ldc + (size_t)(n & 511) * 4 + (n >> 9))
                                  : ((size_t)m * ldc + n);
        C[idx] = v;
      }
    }
  }
}

// ---------------------------------------------------------------------------
// amax word: [val:f32 bits in high 32][tag:16][token:16]; tag(t) = t+2.
// ---------------------------------------------------------------------------
__global__ __launch_bounds__(256) void init_kernel(
    const float* __restrict__ ctx, float* __restrict__ hbuf,
    unsigned long long* __restrict__ amax,
    int* __restrict__ hdone, const int* __restrict__ start_id)
{
  const int i = blockIdx.x * blockDim.x + threadIdx.x;
  // h(-1) = context into slot 1
  ((float4*)(hbuf + B_ * H_))[i] = ((const float4*)ctx)[i];
  if (i < B_ * 32) {
    const int m = i & 31;
    const unsigned long long w = (m == 0)
        ? ((((unsigned long long)__float_as_uint(FLT_MAX)) << 32) |
           (1u << 16) | (unsigned)(*start_id))
        : ((((unsigned long long)__float_as_uint(-FLT_MAX)) << 32) | (1u << 16));
    amax[(size_t)B_ * 32 + i] = w;   // parity-1 slot, tag(-1)=1
  }
  if (i < 2 * 8 * 32) hdone[i * 16] = 0;
}

// ---------------------------------------------------------------------------
// Persistent cooperative decoder, 512 threads (8 waves, 2/SIMD).
// 8 groups x 32 blocks; group g owns rows [16g,16g+16).  Tagged-dataflow sync.
//
// Round-6 structure:
//  * K-parity split kept (wave w -> blk=w&3 gate/vocab-octet, par=w>>2 K-half;
//    lane q1=lane>>4, kc=lane&15 -> 16-float K-chunk).  Weights 96 VGPR/lane.
//  * hs STRIDE-20 CHUNKS: chunk cc = par*16+kc lives at col cc*20 (80 B,
//    16B-aligned).  Chunk base banks (20cc)%32 spread over 8 distinct 4-bank
//    groups, 2 lanes each -> 2-way (free, m136); r5's linear layout was 8-way
//    (banks {0,16} only) -> 8.08e8 conflicts.
//  * MERGED h-pass: logits(t) and gate-partials(t+1) computed from ONE chunk
//    read (P2(t) and P1(t+1) both consume h(t)) -> 512 ds_read_b128/blk/step.
//    amax poll returns to loop top (round-4 ordering, verified); its ~0.3us
//    exposure is bought for ~1.7us less LDS time.
//  * Fault-proofed: bounded spins + token clamp (no hang, no OOB).
// ---------------------------------------------------------------------------
__global__ __launch_bounds__(512, 2) void decoder_main(
    const float* __restrict__ Whh,
    const float* __restrict__ Wout,
    const float* __restrict__ bout,
    const float* __restrict__ proj,
    const float* __restrict__ basep,
    float* __restrict__ hbuf,
    unsigned long long* __restrict__ amax,
    int* __restrict__ hdone,
    float* __restrict__ out)
{
  __shared__ struct alignas(16) SM {
    float hs[16][640];          // h tile: chunk cc at col cc*20 (16 used, 4 pad)
    float gbase[16][68];        // interleaved basep slice [r][u*4+g]
    float gbuf2[2][16][68];     // gate partials per K-parity (for step t+1)
    float lbuf2[2][16][34];     // logit partials per K-parity (for step t)
    float sbout[32];
    int   tok[16];
  } sm;

  const int tid  = threadIdx.x;
  const int bid  = blockIdx.x;
  const int gid  = bid >> 5;     // group: rows [16g, 16g+16)
  const int mem  = bid & 31;     // member: units [16*mem,+16) / vocab [32*mem,+32)
  const int lane = tid & 63;
  const int w    = tid >> 6;     // wave 0..7
  const int row_base = gid * 16;
  const int vb   = mem * 32;

  const int q1  = lane >> 4;     // 0..3
  const int kc  = lane & 15;     // 16-float K-chunk within the K-half
  const int blk = w & 3;         // gate index / vocab-octet
  const int par = w >> 2;        // K-half 0/1
  const int hoff  = par * 256 + kc * 16;     // K offset in weights (logical)
  const int hcol  = (par * 16 + kc) * 20;    // hs column of this chunk

  // ---- one-time preloads: weights -> registers (96 VGPR, no duplication) --
  float4 w1r[4][4];              // 4 gate-lines x 16 floats
#pragma unroll
  for (int i = 0; i < 4; ++i) {
    const float* p = Whh + (size_t)(blk * 512 + mem * 16 + q1 * 4 + i) * H_ + hoff;
#pragma unroll
    for (int j = 0; j < 4; ++j) w1r[i][j] = *(const float4*)(p + j * 4);
  }
  const int v0 = vb + blk * 8 + q1 * 2;
  float4 w2r[2][4];              // 2 vocab x 16 floats
#pragma unroll
  for (int jj = 0; jj < 2; ++jj) {
    const int vv = (v0 + jj < V_) ? (v0 + jj) : (V_ - 1);
    const float* p = Wout + (size_t)vv * H_ + hoff;
#pragma unroll
    for (int j = 0; j < 4; ++j) w2r[jj][j] = *(const float4*)(p + j * 4);
  }

  // basep slice (interleaved) -> LDS; bout slice -> LDS
#pragma unroll
  for (int kx = 0; kx < 2; ++kx) {
    const int e = tid + kx * 512;
    const int r = e >> 6, c = e & 63;
    sm.gbase[r][c] = basep[(size_t)(row_base + r) * G4_ + mem * 64 + c];
  }
  if (tid < 32) sm.sbout[tid] = (vb + tid < V_) ? bout[vb + tid] : 0.f;

  float c_reg = 0.f;   // tid<256 owns cell (row=row_base+(tid>>4), unit=mem*16+(tid&15))
  const size_t BTVo = (size_t)B_ * T_ * V_;

  // ---- prepass: stage h(-1)=context; gate-only pass fills gbuf2 ----------
  {
    const unsigned long long* hq =
        (const unsigned long long*)(hbuf + (size_t)B_ * H_ + (size_t)row_base * H_);
    unsigned long long v[8];
#pragma unroll
    for (int i = 0; i < 8; ++i) v[i] = AT_LOAD(&hq[tid + i * 512]);
#pragma unroll
    for (int i = 0; i < 8; ++i) {
      const int idx = tid + i * 512;
      const int row = idx >> 8, cp = idx & 255;
      *(unsigned long long*)&sm.hs[row][(cp >> 3) * 20 + (cp & 7) * 2] = v[i];
    }
  }
  __syncthreads();
#pragma unroll 1
  for (int r = 0; r < 16; ++r) {
    const float* hr = &sm.hs[r][hcol];
    const float4 h0 = *(const float4*)(hr + 0);
    const float4 h1 = *(const float4*)(hr + 4);
    const float4 h2 = *(const float4*)(hr + 8);
    const float4 h3 = *(const float4*)(hr + 12);
    float a0 = dot4(w1r[0][3], h3, dot4(w1r[0][2], h2, dot4(w1r[0][1], h1, dot4(w1r[0][0], h0, 0.f))));
    float a1 = dot4(w1r[1][3], h3, dot4(w1r[1][2], h2, dot4(w1r[1][1], h1, dot4(w1r[1][0], h0, 0.f))));
    float a2 = dot4(w1r[2][3], h3, dot4(w1r[2][2], h2, dot4(w1r[2][1], h1, dot4(w1r[2][0], h0, 0.f))));
    float a3 = dot4(w1r[3][3], h3, dot4(w1r[3][2], h2, dot4(w1r[3][1], h1, dot4(w1r[3][0], h0, 0.f))));
    a0 = red16(a0); a1 = red16(a1); a2 = red16(a2); a3 = red16(a3);
    if (kc < 4) {
      const float av = (kc == 0) ? a0 : (kc == 1) ? a1 : (kc == 2) ? a2 : a3;
      sm.gbuf2[par][r][(q1 * 4 + kc) * 4 + blk] = av;
    }
  }
  __syncthreads();

  for (int t = 0; t < T_; ++t) {
    float* hdst = hbuf + (size_t)(t & 1) * (B_ * H_);

    // ---- B: poll amax(t-1) -> tok[] --------------------------------------
    {
      const int prow = tid >> 5, pj = tid & 31;
      const unsigned expect = (unsigned)(t + 1) << 16;   // tag(t-1) = t+1
      const unsigned long long* ap =
          amax + ((size_t)((t + 1) & 1) * B_ + row_base + prow) * 32;
      unsigned long long wv = AT_LOAD(&ap[pj]);
      for (int it = 0; (((unsigned)wv ^ expect) & 0xFFFF0000u) && it < SPIN_MAX; ++it) {
        __builtin_amdgcn_s_sleep(1);
        wv = AT_LOAD(&ap[pj]);
      }
      __atomic_signal_fence(__ATOMIC_ACQ_REL);
      float v  = __uint_as_float((unsigned)(wv >> 32));
      int   ix = (int)((unsigned)wv & 0xFFFFu);
#pragma unroll
      for (int d = 16; d >= 1; d >>= 1) {
        const float vo = __shfl_xor(v, d, 32);
        const int   io = __shfl_xor(ix, d, 32);
        if (vo > v || (vo == v && io < ix)) { v = vo; ix = io; }
      }
      if (pj == 0) sm.tok[prow] = (ix >= 0 && ix < V_) ? ix : 0;   // clamp
    }
    __syncthreads();

    // ---- D: LSTM epilogue (tid<256): combine parities + proj + gbase ----
    if (tid < 256) {
      const int rl = tid >> 4, ul = tid & 15;
      const int tk = sm.tok[rl];
      const float4 ga = *(const float4*)&sm.gbuf2[0][rl][ul * 4];
      const float4 gb = *(const float4*)&sm.gbuf2[1][rl][ul * 4];
      const float4 gc = *(const float4*)&sm.gbase[rl][ul * 4];
      const float4 gp = *(const float4*)&proj[(size_t)tk * G4_ + (size_t)(mem * 16 + ul) * 4];
      const float gx = ga.x + gb.x + gc.x + gp.x;
      const float gy = ga.y + gb.y + gc.y + gp.y;
      const float gz = ga.z + gb.z + gc.z + gp.z;
      const float gw = ga.w + gb.w + gc.w + gp.w;
      const float ig = 1.f / (1.f + expf(-gx));
      const float fg = 1.f / (1.f + expf(-gy));
      const float gg = tanhf(gz);
      const float og = 1.f / (1.f + expf(-gw));
      const float cn = fg * c_reg + ig * gg;
      c_reg = cn;
      const float hn = og * tanhf(cn);
      const int row = row_base + rl, hid = mem * 16 + ul;
      const float hn2 = __shfl_down(hn, 1);
      if ((ul & 1) == 0) {
        const unsigned long long pk =
            (unsigned long long)__float_as_uint(hn) |
            (((unsigned long long)__float_as_uint(hn2)) << 32);
        AT_STORE((unsigned long long*)&hdst[(size_t)row * H_ + hid], pk);
      }
      if (t == T_ - 1) {
        out[BTVo + (size_t)row * H_ + hid] = hn;                    // h_f
        out[BTVo + (size_t)B_ * H_ + (size_t)row * H_ + hid] = cn;  // c_f
      }
    }
    __syncthreads();   // drains vmcnt -> release for hdone flag
    if (tid == 0)
      AT_STORE(&hdone[(((t & 1) * 8 + gid) * 32 + mem) * 16], t + 2);

    // ---- E: wait for all members' h(t) ----------------------------------
    if (tid < 32) {
      int* fp = &hdone[(((t & 1) * 8 + gid) * 32 + tid) * 16];
      for (int it = 0; AT_LOAD(fp) != t + 2 && it < SPIN_MAX; ++it)
        __builtin_amdgcn_s_sleep(1);
    }
    __atomic_signal_fence(__ATOMIC_ACQ_REL);
    __syncthreads();

    // ---- F: stage h(t) into hs (stride-20 chunks) -----------------------
    {
      const unsigned long long* hq =
          (const unsigned long long*)(hdst + (size_t)row_base * H_);
      unsigned long long v[8];
#pragma unroll
      for (int i = 0; i < 8; ++i) v[i] = AT_LOAD(&hq[tid + i * 512]);
#pragma unroll
      for (int i = 0; i < 8; ++i) {
        const int idx = tid + i * 512;
        const int row = idx >> 8, cp = idx & 255;
        *(unsigned long long*)&sm.hs[row][(cp >> 3) * 20 + (cp & 7) * 2] = v[i];
      }
    }
    __syncthreads();

    // ---- MERGED: logits(t) + gate-partials(t+1) from ONE chunk read -----
#pragma unroll 1
    for (int r = 0; r < 16; ++r) {
      const float* hr = &sm.hs[r][hcol];
      const float4 h0 = *(const float4*)(hr + 0);
      const float4 h1 = *(const float4*)(hr + 4);
      const float4 h2 = *(const float4*)(hr + 8);
      const float4 h3 = *(const float4*)(hr + 12);
      float a0 = dot4(w1r[0][3], h3, dot4(w1r[0][2], h2, dot4(w1r[0][1], h1, dot4(w1r[0][0], h0, 0.f))));
      float a1 = dot4(w1r[1][3], h3, dot4(w1r[1][2], h2, dot4(w1r[1][1], h1, dot4(w1r[1][0], h0, 0.f))));
      float a2 = dot4(w1r[2][3], h3, dot4(w1r[2][2], h2, dot4(w1r[2][1], h1, dot4(w1r[2][0], h0, 0.f))));
      float a3 = dot4(w1r[3][3], h3, dot4(w1r[3][2], h2, dot4(w1r[3][1], h1, dot4(w1r[3][0], h0, 0.f))));
      float b0 = dot4(w2r[0][3], h3, dot4(w2r[0][2], h2, dot4(w2r[0][1], h1, dot4(w2r[0][0], h0, 0.f))));
      float b1 = dot4(w2r[1][3], h3, dot4(w2r[1][2], h2, dot4(w2r[1][1], h1, dot4(w2r[1][0], h0, 0.f))));
      a0 = red16(a0); a1 = red16(a1); a2 = red16(a2); a3 = red16(a3);
      b0 = red16(b0); b1 = red16(b1);
      if (kc < 4) {
        const float av = (kc == 0) ? a0 : (kc == 1) ? a1 : (kc == 2) ? a2 : a3;
        sm.gbuf2[par][r][(q1 * 4 + kc) * 4 + blk] = av;
      }
      if (kc < 2)
        sm.lbuf2[par][r][blk * 8 + q1 * 2 + kc] = (kc == 0) ? b0 : b1;
    }
    __syncthreads();

    // ---- H: combine parities, write logits, argmax -> amax --------------
    {
      const int r = tid >> 5, j = tid & 31;
      float v = sm.lbuf2[0][r][j] + sm.lbuf2[1][r][j] + sm.sbout[j];
      if (vb + j < V_)
        out[((size_t)(row_base + r) * T_ + t) * V_ + vb + j] = v;
      else
        v = -FLT_MAX;
      int ix = j;
#pragma unroll
      for (int d = 16; d >= 1; d >>= 1) {
        const float vo = __shfl_xor(v, d, 32);
        const int   io = __shfl_xor(ix, d, 32);
        if (vo > v || (vo == v && io < ix)) { v = vo; ix = io; }
      }
      if (j == 0) {
        const unsigned long long pk =
            (((unsigned long long)__float_as_uint(v)) << 32) |
            ((unsigned)(t + 2) << 16) | (unsigned)(vb + ix);
        AT_STORE(&amax[((size_t)(t & 1) * B_ + row_base + r) * 32 + mem], pk);
      }
    }
    // no barrier: next iteration's B polls global amax; gbuf2 (for D) was
    // written before the post-merged barrier; lbuf2 is rewritten only after
    // the next F barrier chain.
  }
}

// ---------------------------------------------------------------------------
extern "C" void kernel_launch(void* const* d_in, const int* in_sizes, int n_in,
                              void* d_out, int out_size, void* d_ws, size_t ws_size,
                              hipStream_t stream)
{
  const float* ctx   = (const float*)d_in[0];
  const float* emb   = (const float*)d_in[1];
  const float* Wih   = (const float*)d_in[2];
  const float* bih   = (const float*)d_in[3];
  const float* Whh   = (const float*)d_in[4];
  const float* bhh   = (const float*)d_in[5];
  const float* Wout  = (const float*)d_in[6];
  const float* bout  = (const float*)d_in[7];
  const int*   start = (const int*)d_in[8];
  float* out = (float*)d_out;

  // workspace layout (bytes)
  char* ws = (char*)d_ws;
  float* proj  = (float*)(ws + 0);                    // 1000*2048*4 = 8,192,000
  float* basep = (float*)(ws + 8192000);              // 128*2048*4  = 1,048,576
  float* hbuf  = (float*)(ws + 9240576);              // 2*128*512*4 =   524,288
  unsigned long long* amax = (unsigned long long*)(ws + 9764864);  // 2*128*32*8 = 65,536
  int*   hdone = (int*)(ws + 9830400);                // 2*8*32*64B  =    32,768

  hipLaunchKernelGGL(gemm_nt_k512, dim3(32, 2), dim3(256), 0, stream,
                     ctx, B_, Wih, 1024, 0, bih, bhh, basep, G4_, 1);
  hipLaunchKernelGGL(gemm_nt_k512, dim3(32, 16), dim3(256), 0, stream,
                     emb, V_, Wih, 1024, 512, (const float*)nullptr, (const float*)nullptr,
                     proj, G4_, 1);
  hipLaunchKernelGGL(init_kernel, dim3(64), dim3(256), 0, stream,
                     ctx, hbuf, amax, hdone, start);

  void* args[] = {(void*)&Whh, (void*)&Wout, (void*)&bout, (void*)&proj, (void*)&basep,
                  (void*)&hbuf, (void*)&amax, (void*)&hdone, (void*)&out};
  hipLaunchCooperativeKernel(reinterpret_cast<const void*>(decoder_main),
                             dim3(NBLK), dim3(512), args, 0, stream);
}

// Round 7
// 3077.776 us; speedup vs baseline: 1.2047x; 1.2047x over previous
//
#include <hip/hip_runtime.h>
#include <float.h>
#include <math.h>

#define B_    128
#define H_    512
#define V_    1000
#define T_    256
#define G4_   2048
#define NBLK  256          // cooperative launch: 1 block/CU
#define SPIN_MAX (1 << 17) // bounded spin: converts would-be hang into wrong-answer

#define AT_LOAD(p)    __hip_atomic_load((p), __ATOMIC_RELAXED, __HIP_MEMORY_SCOPE_AGENT)
#define AT_STORE(p,v) __hip_atomic_store((p), (v), __ATOMIC_RELAXED, __HIP_MEMORY_SCOPE_AGENT)

// Pin a float4 in VGPRs: the value now originates from a volatile asm def,
// so the register allocator cannot rematerialize the original global load
// inside the decode loop (r4/r6 evidence: VGPR_Count 88 < 96 declared ->
// weights were being re-streamed from L2 every step).
#define PIN4(v_) asm volatile("" : "+v"((v_).x), "+v"((v_).y), "+v"((v_).z), "+v"((v_).w))

__device__ __forceinline__ float dot4(float4 a, float4 b, float acc) {
  return fmaf(a.x, b.x, fmaf(a.y, b.y, fmaf(a.z, b.z, fmaf(a.w, b.w, acc))));
}

// 16-lane butterfly sum, pure DPP (VALU pipe, zero LDS traffic).
__device__ __forceinline__ float red16(float x) {
  x += __int_as_float(__builtin_amdgcn_mov_dpp(__float_as_int(x), 0xB1,  0xF, 0xF, true));
  x += __int_as_float(__builtin_amdgcn_mov_dpp(__float_as_int(x), 0x4E,  0xF, 0xF, true));
  x += __int_as_float(__builtin_amdgcn_mov_dpp(__float_as_int(x), 0x141, 0xF, 0xF, true));
  x += __int_as_float(__builtin_amdgcn_mov_dpp(__float_as_int(x), 0x140, 0xF, 0xF, true));
  return x;
}

// ---------------------------------------------------------------------------
// Precompute GEMM:  C = A[M][0:512] * Bm[N][koff:+512]^T (+bias1+bias2).
// ileave=1 stores gate-interleaved: C[m][ (n&511)*4 + (n>>9) ]  (ldc=2048).
// ---------------------------------------------------------------------------
__global__ __launch_bounds__(256) void gemm_nt_k512(
    const float* __restrict__ A, int M,
    const float* __restrict__ Bm, int ldb, int koff,
    const float* __restrict__ bias1, const float* __restrict__ bias2,
    float* __restrict__ C, int ldc, int ileave)
{
  __shared__ float As[16][68];
  __shared__ float Bs[16][68];
  const int tid = threadIdx.x;
  const int m0 = blockIdx.y * 64, n0 = blockIdx.x * 64;
  const int tm = tid & 15, tn = tid >> 4;
  const int lm = tid & 63, kq = tid >> 6;
  float acc[4][4] = {};
  for (int k0 = 0; k0 < 512; k0 += 16) {
    float4 av = make_float4(0.f, 0.f, 0.f, 0.f);
    if (m0 + lm < M) av = *(const float4*)(A + (size_t)(m0 + lm) * 512 + k0 + kq * 4);
    float4 bv = *(const float4*)(Bm + (size_t)(n0 + lm) * ldb + koff + k0 + kq * 4);
    __syncthreads();
    As[kq*4+0][lm] = av.x; As[kq*4+1][lm] = av.y; As[kq*4+2][lm] = av.z; As[kq*4+3][lm] = av.w;
    Bs[kq*4+0][lm] = bv.x; Bs[kq*4+1][lm] = bv.y; Bs[kq*4+2][lm] = bv.z; Bs[kq*4+3][lm] = bv.w;
    __syncthreads();
#pragma unroll
    for (int kk = 0; kk < 16; ++kk) {
      const float4 a = *(const float4*)&As[kk][tm * 4];
      const float4 b = *(const float4*)&Bs[kk][tn * 4];
      const float aa[4] = {a.x, a.y, a.z, a.w};
      const float bb[4] = {b.x, b.y, b.z, b.w};
#pragma unroll
      for (int i = 0; i < 4; ++i)
#pragma unroll
        for (int j = 0; j < 4; ++j)
          acc[i][j] = fmaf(aa[i], bb[j], acc[i][j]);
    }
  }
#pragma unroll
  for (int i = 0; i < 4; ++i) {
    const int m = m0 + tm * 4 + i;
    if (m < M) {
#pragma unroll
      for (int j = 0; j < 4; ++j) {
        const int n = n0 + tn * 4 + j;
        float v = acc[i][j];
        if (bias1) v += bias1[n];
        if (bias2) v += bias2[n];
        const size_t idx = ileave ? ((size_t)m * ldc + (size_t)(n & 511) * 4 + (n >> 9))
                                  : ((size_t)m * ldc + n);
        C[idx] = v;
      }
    }
  }
}

// ---------------------------------------------------------------------------
// amax word: [val:f32 bits in high 32][tag:16][token:16]; tag(t) = t+2.
// ---------------------------------------------------------------------------
__global__ __launch_bounds__(256) void init_kernel(
    const float* __restrict__ ctx, float* __restrict__ hbuf,
    unsigned long long* __restrict__ amax,
    int* __restrict__ hdone, const int* __restrict__ start_id)
{
  const int i = blockIdx.x * blockDim.x + threadIdx.x;
  // h(-1) = context into slot 1
  ((float4*)(hbuf + B_ * H_))[i] = ((const float4*)ctx)[i];
  if (i < B_ * 32) {
    const int m = i & 31;
    const unsigned long long w = (m == 0)
        ? ((((unsigned long long)__float_as_uint(FLT_MAX)) << 32) |
           (1u << 16) | (unsigned)(*start_id))
        : ((((unsigned long long)__float_as_uint(-FLT_MAX)) << 32) | (1u << 16));
    amax[(size_t)B_ * 32 + i] = w;   // parity-1 slot, tag(-1)=1
  }
  if (i < 2 * 8 * 32) hdone[i * 16] = 0;
}

// ---------------------------------------------------------------------------
// Persistent cooperative decoder, 512 threads (8 waves, 2/SIMD).
// 8 groups x 32 blocks; group g owns rows [16g,16g+16).  Tagged-dataflow sync.
//
// Round-7 structure:
//  * K-parity split (wave w -> blk=w&3 gate/vocab-octet, par=w>>2 K-half;
//    lane q1=lane>>4, kc=lane&15 -> 16-float K-chunk).
//  * Weights PINNED in VGPRs via asm laundering (96/lane) -- r4/r6 showed the
//    compiler rematerializing the loads into the loop (VGPR=88 < 96 needed).
//  * hs stride-20 chunk layout (r6): conflict-free staging + chunk reads.
//  * r5 phase order (P1 -> poll -> D -> exchange -> P2 -> H): the amax(t-1)
//    round-trip hides under P1's ~2us of gate GEMM (r6's merged pass exposed
//    it and lost 284us).
//  * Fault-proofed: bounded spins + token clamp (no hang, no OOB).
// ---------------------------------------------------------------------------
__global__ __launch_bounds__(512, 2) void decoder_main(
    const float* __restrict__ Whh,
    const float* __restrict__ Wout,
    const float* __restrict__ bout,
    const float* __restrict__ proj,
    const float* __restrict__ basep,
    float* __restrict__ hbuf,
    unsigned long long* __restrict__ amax,
    int* __restrict__ hdone,
    float* __restrict__ out)
{
  __shared__ struct alignas(16) SM {
    float hs[16][640];          // h tile: chunk cc at col cc*20 (16 used, 4 pad)
    float gbase[16][68];        // interleaved basep slice [r][u*4+g]
    float gbuf2[2][16][68];     // gate partials per K-parity
    float lbuf2[2][16][34];     // logit partials per K-parity
    float sbout[32];
    int   tok[16];
  } sm;

  const int tid  = threadIdx.x;
  const int bid  = blockIdx.x;
  const int gid  = bid >> 5;     // group: rows [16g, 16g+16)
  const int mem  = bid & 31;     // member: units [16*mem,+16) / vocab [32*mem,+32)
  const int lane = tid & 63;
  const int w    = tid >> 6;     // wave 0..7
  const int row_base = gid * 16;
  const int vb   = mem * 32;

  const int q1  = lane >> 4;     // 0..3
  const int kc  = lane & 15;     // 16-float K-chunk within the K-half
  const int blk = w & 3;         // gate index / vocab-octet
  const int par = w >> 2;        // K-half 0/1
  const int hoff  = par * 256 + kc * 16;     // K offset in weights (logical)
  const int hcol  = (par * 16 + kc) * 20;    // hs column of this chunk

  // ---- one-time preloads: weights -> registers, PINNED -------------------
  float4 w1r[4][4];              // 4 gate-lines x 16 floats = 64 VGPR
#pragma unroll
  for (int i = 0; i < 4; ++i) {
    const float* p = Whh + (size_t)(blk * 512 + mem * 16 + q1 * 4 + i) * H_ + hoff;
#pragma unroll
    for (int j = 0; j < 4; ++j) w1r[i][j] = *(const float4*)(p + j * 4);
  }
  const int v0 = vb + blk * 8 + q1 * 2;
  float4 w2r[2][4];              // 2 vocab x 16 floats = 32 VGPR
#pragma unroll
  for (int jj = 0; jj < 2; ++jj) {
    const int vv = (v0 + jj < V_) ? (v0 + jj) : (V_ - 1);
    const float* p = Wout + (size_t)vv * H_ + hoff;
#pragma unroll
    for (int j = 0; j < 4; ++j) w2r[jj][j] = *(const float4*)(p + j * 4);
  }
#pragma unroll
  for (int i = 0; i < 4; ++i) {
    PIN4(w1r[i][0]); PIN4(w1r[i][1]); PIN4(w1r[i][2]); PIN4(w1r[i][3]);
  }
#pragma unroll
  for (int jj = 0; jj < 2; ++jj) {
    PIN4(w2r[jj][0]); PIN4(w2r[jj][1]); PIN4(w2r[jj][2]); PIN4(w2r[jj][3]);
  }

  // basep slice (interleaved) -> LDS; bout slice -> LDS
#pragma unroll
  for (int kx = 0; kx < 2; ++kx) {
    const int e = tid + kx * 512;
    const int r = e >> 6, c = e & 63;
    sm.gbase[r][c] = basep[(size_t)(row_base + r) * G4_ + mem * 64 + c];
  }
  if (tid < 32) sm.sbout[tid] = (vb + tid < V_) ? bout[vb + tid] : 0.f;

  float c_reg = 0.f;   // tid<256 owns cell (row=row_base+(tid>>4), unit=mem*16+(tid&15))
  const size_t BTVo = (size_t)B_ * T_ * V_;

  // ---- prepass: stage h(-1)=context into hs (stride-20 chunks) -----------
  {
    const unsigned long long* hq =
        (const unsigned long long*)(hbuf + (size_t)B_ * H_ + (size_t)row_base * H_);
    unsigned long long v[8];
#pragma unroll
    for (int i = 0; i < 8; ++i) v[i] = AT_LOAD(&hq[tid + i * 512]);
#pragma unroll
    for (int i = 0; i < 8; ++i) {
      const int idx = tid + i * 512;
      const int row = idx >> 8, cp = idx & 255;
      *(unsigned long long*)&sm.hs[row][(cp >> 3) * 20 + (cp & 7) * 2] = v[i];
    }
  }
  __syncthreads();

  for (int t = 0; t < T_; ++t) {
    float* hdst = hbuf + (size_t)(t & 1) * (B_ * H_);

    // ---- P1: gates(t) partials = Whh_half * h(t-1) -> gbuf2[par] ---------
#pragma unroll 1
    for (int r = 0; r < 16; ++r) {
      const float* hr = &sm.hs[r][hcol];
      const float4 h0 = *(const float4*)(hr + 0);
      const float4 h1 = *(const float4*)(hr + 4);
      const float4 h2 = *(const float4*)(hr + 8);
      const float4 h3 = *(const float4*)(hr + 12);
      float a0 = dot4(w1r[0][3], h3, dot4(w1r[0][2], h2, dot4(w1r[0][1], h1, dot4(w1r[0][0], h0, 0.f))));
      float a1 = dot4(w1r[1][3], h3, dot4(w1r[1][2], h2, dot4(w1r[1][1], h1, dot4(w1r[1][0], h0, 0.f))));
      float a2 = dot4(w1r[2][3], h3, dot4(w1r[2][2], h2, dot4(w1r[2][1], h1, dot4(w1r[2][0], h0, 0.f))));
      float a3 = dot4(w1r[3][3], h3, dot4(w1r[3][2], h2, dot4(w1r[3][1], h1, dot4(w1r[3][0], h0, 0.f))));
      a0 = red16(a0); a1 = red16(a1); a2 = red16(a2); a3 = red16(a3);
      if (kc < 4) {
        const float av = (kc == 0) ? a0 : (kc == 1) ? a1 : (kc == 2) ? a2 : a3;
        sm.gbuf2[par][r][(q1 * 4 + kc) * 4 + blk] = av;
      }
    }

    // ---- B: poll amax(t-1) -> tok[]  (propagation hidden under P1) ------
    {
      const int prow = tid >> 5, pj = tid & 31;
      const unsigned expect = (unsigned)(t + 1) << 16;   // tag(t-1) = t+1
      const unsigned long long* ap =
          amax + ((size_t)((t + 1) & 1) * B_ + row_base + prow) * 32;
      unsigned long long wv = AT_LOAD(&ap[pj]);
      for (int it = 0; (((unsigned)wv ^ expect) & 0xFFFF0000u) && it < SPIN_MAX; ++it) {
        __builtin_amdgcn_s_sleep(1);
        wv = AT_LOAD(&ap[pj]);
      }
      __atomic_signal_fence(__ATOMIC_ACQ_REL);
      float v  = __uint_as_float((unsigned)(wv >> 32));
      int   ix = (int)((unsigned)wv & 0xFFFFu);
#pragma unroll
      for (int d = 16; d >= 1; d >>= 1) {
        const float vo = __shfl_xor(v, d, 32);
        const int   io = __shfl_xor(ix, d, 32);
        if (vo > v || (vo == v && io < ix)) { v = vo; ix = io; }
      }
      if (pj == 0) sm.tok[prow] = (ix >= 0 && ix < V_) ? ix : 0;   // clamp
    }
    __syncthreads();

    // ---- D: LSTM epilogue (tid<256): combine parities + proj + gbase ----
    if (tid < 256) {
      const int rl = tid >> 4, ul = tid & 15;
      const int tk = sm.tok[rl];
      const float4 ga = *(const float4*)&sm.gbuf2[0][rl][ul * 4];
      const float4 gb = *(const float4*)&sm.gbuf2[1][rl][ul * 4];
      const float4 gc = *(const float4*)&sm.gbase[rl][ul * 4];
      const float4 gp = *(const float4*)&proj[(size_t)tk * G4_ + (size_t)(mem * 16 + ul) * 4];
      const float gx = ga.x + gb.x + gc.x + gp.x;
      const float gy = ga.y + gb.y + gc.y + gp.y;
      const float gz = ga.z + gb.z + gc.z + gp.z;
      const float gw = ga.w + gb.w + gc.w + gp.w;
      const float ig = 1.f / (1.f + expf(-gx));
      const float fg = 1.f / (1.f + expf(-gy));
      const float gg = tanhf(gz);
      const float og = 1.f / (1.f + expf(-gw));
      const float cn = fg * c_reg + ig * gg;
      c_reg = cn;
      const float hn = og * tanhf(cn);
      const int row = row_base + rl, hid = mem * 16 + ul;
      const float hn2 = __shfl_down(hn, 1);
      if ((ul & 1) == 0) {
        const unsigned long long pk =
            (unsigned long long)__float_as_uint(hn) |
            (((unsigned long long)__float_as_uint(hn2)) << 32);
        AT_STORE((unsigned long long*)&hdst[(size_t)row * H_ + hid], pk);
      }
      if (t == T_ - 1) {
        out[BTVo + (size_t)row * H_ + hid] = hn;                    // h_f
        out[BTVo + (size_t)B_ * H_ + (size_t)row * H_ + hid] = cn;  // c_f
      }
    }
    __syncthreads();   // drains vmcnt -> release for hdone flag
    if (tid == 0)
      AT_STORE(&hdone[(((t & 1) * 8 + gid) * 32 + mem) * 16], t + 2);

    // ---- E: wait for all members' h(t) ----------------------------------
    if (tid < 32) {
      int* fp = &hdone[(((t & 1) * 8 + gid) * 32 + tid) * 16];
      for (int it = 0; AT_LOAD(fp) != t + 2 && it < SPIN_MAX; ++it)
        __builtin_amdgcn_s_sleep(1);
    }
    __atomic_signal_fence(__ATOMIC_ACQ_REL);
    __syncthreads();

    // ---- F: stage h(t) into hs (stride-20 chunks) -----------------------
    {
      const unsigned long long* hq =
          (const unsigned long long*)(hdst + (size_t)row_base * H_);
      unsigned long long v[8];
#pragma unroll
      for (int i = 0; i < 8; ++i) v[i] = AT_LOAD(&hq[tid + i * 512]);
#pragma unroll
      for (int i = 0; i < 8; ++i) {
        const int idx = tid + i * 512;
        const int row = idx >> 8, cp = idx & 255;
        *(unsigned long long*)&sm.hs[row][(cp >> 3) * 20 + (cp & 7) * 2] = v[i];
      }
    }
    __syncthreads();

    // ---- P2: logits(t) partials = Wout_half * h(t) -> lbuf2[par] --------
#pragma unroll 1
    for (int r = 0; r < 16; ++r) {
      const float* hr = &sm.hs[r][hcol];
      const float4 h0 = *(const float4*)(hr + 0);
      const float4 h1 = *(const float4*)(hr + 4);
      const float4 h2 = *(const float4*)(hr + 8);
      const float4 h3 = *(const float4*)(hr + 12);
      float b0 = dot4(w2r[0][3], h3, dot4(w2r[0][2], h2, dot4(w2r[0][1], h1, dot4(w2r[0][0], h0, 0.f))));
      float b1 = dot4(w2r[1][3], h3, dot4(w2r[1][2], h2, dot4(w2r[1][1], h1, dot4(w2r[1][0], h0, 0.f))));
      b0 = red16(b0); b1 = red16(b1);
      if (kc < 2)
        sm.lbuf2[par][r][blk * 8 + q1 * 2 + kc] = (kc == 0) ? b0 : b1;
    }
    __syncthreads();

    // ---- H: combine parities, write logits, argmax -> amax --------------
    {
      const int r = tid >> 5, j = tid & 31;
      float v = sm.lbuf2[0][r][j] + sm.lbuf2[1][r][j] + sm.sbout[j];
      if (vb + j < V_)
        out[((size_t)(row_base + r) * T_ + t) * V_ + vb + j] = v;
      else
        v = -FLT_MAX;
      int ix = j;
#pragma unroll
      for (int d = 16; d >= 1; d >>= 1) {
        const float vo = __shfl_xor(v, d, 32);
        const int   io = __shfl_xor(ix, d, 32);
        if (vo > v || (vo == v && io < ix)) { v = vo; ix = io; }
      }
      if (j == 0) {
        const unsigned long long pk =
            (((unsigned long long)__float_as_uint(v)) << 32) |
            ((unsigned)(t + 2) << 16) | (unsigned)(vb + ix);
        AT_STORE(&amax[((size_t)(t & 1) * B_ + row_base + r) * 32 + mem], pk);
      }
    }
    // no barrier: next iteration's P1 reads hs (stable until next F) and
    // writes gbuf2 (last read by D(t), separated by multiple barriers).
  }
}

// ---------------------------------------------------------------------------
extern "C" void kernel_launch(void* const* d_in, const int* in_sizes, int n_in,
                              void* d_out, int out_size, void* d_ws, size_t ws_size,
                              hipStream_t stream)
{
  const float* ctx   = (const float*)d_in[0];
  const float* emb   = (const float*)d_in[1];
  const float* Wih   = (const float*)d_in[2];
  const float* bih   = (const float*)d_in[3];
  const float* Whh   = (const float*)d_in[4];
  const float* bhh   = (const float*)d_in[5];
  const float* Wout  = (const float*)d_in[6];
  const float* bout  = (const float*)d_in[7];
  const int*   start = (const int*)d_in[8];
  float* out = (float*)d_out;

  // workspace layout (bytes)
  char* ws = (char*)d_ws;
  float* proj  = (float*)(ws + 0);                    // 1000*2048*4 = 8,192,000
  float* basep = (float*)(ws + 8192000);              // 128*2048*4  = 1,048,576
  float* hbuf  = (float*)(ws + 9240576);              // 2*128*512*4 =   524,288
  unsigned long long* amax = (unsigned long long*)(ws + 9764864);  // 2*128*32*8 = 65,536
  int*   hdone = (int*)(ws + 9830400);                // 2*8*32*64B  =    32,768

  hipLaunchKernelGGL(gemm_nt_k512, dim3(32, 2), dim3(256), 0, stream,
                     ctx, B_, Wih, 1024, 0, bih, bhh, basep, G4_, 1);
  hipLaunchKernelGGL(gemm_nt_k512, dim3(32, 16), dim3(256), 0, stream,
                     emb, V_, Wih, 1024, 512, (const float*)nullptr, (const float*)nullptr,
                     proj, G4_, 1);
  hipLaunchKernelGGL(init_kernel, dim3(64), dim3(256), 0, stream,
                     ctx, hbuf, amax, hdone, start);

  void* args[] = {(void*)&Whh, (void*)&Wout, (void*)&bout, (void*)&proj, (void*)&basep,
                  (void*)&hbuf, (void*)&amax, (void*)&hdone, (void*)&out};
  hipLaunchCooperativeKernel(reinterpret_cast<const void*>(decoder_main),
                             dim3(NBLK), dim3(512), args, 0, stream);
}